// Round 1
// baseline (263.916 us; speedup 1.0000x reference)
//
#include <hip/hip_runtime.h>
#include <math.h>

// EWRLS level filter. Reference recurrence collapses:
//   K = P/(lam+P); P' = K  =>  Q=1/P: Q' = lam*Q + 1, Q0 = 1
//   S_t = Q_t * theta_t obeys S_t = lam*S_{t-1} + x_t, S_0 = x_0
//   theta_t = S_t / Q_t,  Q_t = (1 - lam^{t+1}) / (1 - lam)
// Pure per-channel decay scan -> chunked-parallel over T.

namespace {
constexpr int kB = 64;
constexpr int kT = 1024;
constexpr int kC = 512;
constexpr int kNCH = 16;            // chunks along T
constexpr int kL = kT / kNCH;       // 64 steps per chunk
constexpr int kCV = kC / 4;         // 128 float4 lanes per row
}

__device__ __forceinline__ void load_lam(const float* __restrict__ zl, int c0,
                                         float lam[4]) {
  float4 z = *reinterpret_cast<const float4*>(zl + c0);
  float zz[4] = {z.x, z.y, z.z, z.w};
#pragma unroll
  for (int k = 0; k < 4; ++k) {
    float s = 1.0f / (1.0f + expf(-zz[k]));
    lam[k] = fminf(fmaxf(s, 1e-4f), 1.0f - 1e-4f);
  }
}

// Phase 1: per-(b, chunk) local decayed sums. Last chunk's carry is never
// consumed, so only kNCH-1 chunks run.
extern "C" __global__ __launch_bounds__(256) void ewrls_carry(
    const float* __restrict__ x, const float* __restrict__ zl,
    float4* __restrict__ carry) {
  int idx = blockIdx.x * 256 + threadIdx.x;
  int cv = idx % kCV;
  int bj = idx / kCV;
  int j = bj % (kNCH - 1);          // wave-uniform: kCV=128 >= 64
  int b = bj / (kNCH - 1);
  float lam[4];
  load_lam(zl, cv * 4, lam);

  const float4* xp = reinterpret_cast<const float4*>(x) +
                     ((size_t)b * kT + (size_t)j * kL) * kCV + cv;
  float s0 = 0.f, s1 = 0.f, s2 = 0.f, s3 = 0.f;
#pragma unroll 4
  for (int t = 0; t < kL; ++t) {
    float4 v = xp[(size_t)t * kCV];
    s0 = fmaf(lam[0], s0, v.x);
    s1 = fmaf(lam[1], s1, v.y);
    s2 = fmaf(lam[2], s2, v.z);
    s3 = fmaf(lam[3], s3, v.w);
  }
  carry[((size_t)b * kNCH + j) * kCV + cv] = make_float4(s0, s1, s2, s3);
}

// Phase 2: fold predecessor carries (<=15 fmas, wave-uniform trip count),
// seed Q from closed form, scan 64 steps, write y = S/Q.
extern "C" __global__ __launch_bounds__(256) void ewrls_out(
    const float* __restrict__ x, const float* __restrict__ zl,
    const float4* __restrict__ carry, float* __restrict__ y) {
  int idx = blockIdx.x * 256 + threadIdx.x;
  int cv = idx % kCV;
  int bj = idx / kCV;
  int j = bj % kNCH;                // wave-uniform
  int b = bj / kNCH;
  float lam[4];
  load_lam(zl, cv * 4, lam);

  float lamL[4];
#pragma unroll
  for (int k = 0; k < 4; ++k) {
    float p = lam[k];
#pragma unroll
    for (int q = 0; q < 6; ++q) p = p * p;   // lam^64
    lamL[k] = p;
  }

  float S[4] = {0.f, 0.f, 0.f, 0.f};
  float pj[4] = {1.f, 1.f, 1.f, 1.f};        // lam^(j*kL)
  for (int i = 0; i < j; ++i) {
    float4 cr = carry[((size_t)b * kNCH + i) * kCV + cv];
    S[0] = fmaf(lamL[0], S[0], cr.x);
    S[1] = fmaf(lamL[1], S[1], cr.y);
    S[2] = fmaf(lamL[2], S[2], cr.z);
    S[3] = fmaf(lamL[3], S[3], cr.w);
    pj[0] *= lamL[0];
    pj[1] *= lamL[1];
    pj[2] *= lamL[2];
    pj[3] *= lamL[3];
  }

  float Q[4];
#pragma unroll
  for (int k = 0; k < 4; ++k) Q[k] = (1.0f - pj[k]) / (1.0f - lam[k]);

  const size_t base = ((size_t)b * kT + (size_t)j * kL) * kCV + cv;
  const float4* xp = reinterpret_cast<const float4*>(x) + base;
  float4* yp = reinterpret_cast<float4*>(y) + base;
#pragma unroll 4
  for (int t = 0; t < kL; ++t) {
    float4 v = xp[(size_t)t * kCV];
    S[0] = fmaf(lam[0], S[0], v.x);
    S[1] = fmaf(lam[1], S[1], v.y);
    S[2] = fmaf(lam[2], S[2], v.z);
    S[3] = fmaf(lam[3], S[3], v.w);
    Q[0] = fmaf(lam[0], Q[0], 1.0f);
    Q[1] = fmaf(lam[1], Q[1], 1.0f);
    Q[2] = fmaf(lam[2], Q[2], 1.0f);
    Q[3] = fmaf(lam[3], Q[3], 1.0f);
    float4 o;
    o.x = S[0] / Q[0];
    o.y = S[1] / Q[1];
    o.z = S[2] / Q[2];
    o.w = S[3] / Q[3];
    yp[(size_t)t * kCV] = o;
  }
}

// Fallback if workspace is too small: fully sequential over T per (b, 4ch).
extern "C" __global__ __launch_bounds__(256) void ewrls_serial(
    const float* __restrict__ x, const float* __restrict__ zl,
    float* __restrict__ y) {
  int idx = blockIdx.x * 256 + threadIdx.x;   // [0, kB*kCV)
  int cv = idx % kCV;
  int b = idx / kCV;
  float lam[4];
  load_lam(zl, cv * 4, lam);
  float S[4] = {0.f, 0.f, 0.f, 0.f};
  float Q[4] = {0.f, 0.f, 0.f, 0.f};
  const size_t base = (size_t)b * kT * kCV + cv;
  const float4* xp = reinterpret_cast<const float4*>(x) + base;
  float4* yp = reinterpret_cast<float4*>(y) + base;
#pragma unroll 4
  for (int t = 0; t < kT; ++t) {
    float4 v = xp[(size_t)t * kCV];
    S[0] = fmaf(lam[0], S[0], v.x);
    S[1] = fmaf(lam[1], S[1], v.y);
    S[2] = fmaf(lam[2], S[2], v.z);
    S[3] = fmaf(lam[3], S[3], v.w);
    Q[0] = fmaf(lam[0], Q[0], 1.0f);
    Q[1] = fmaf(lam[1], Q[1], 1.0f);
    Q[2] = fmaf(lam[2], Q[2], 1.0f);
    Q[3] = fmaf(lam[3], Q[3], 1.0f);
    float4 o;
    o.x = S[0] / Q[0];
    o.y = S[1] / Q[1];
    o.z = S[2] / Q[2];
    o.w = S[3] / Q[3];
    yp[(size_t)t * kCV] = o;
  }
}

extern "C" void kernel_launch(void* const* d_in, const int* in_sizes, int n_in,
                              void* d_out, int out_size, void* d_ws,
                              size_t ws_size, hipStream_t stream) {
  const float* x = (const float*)d_in[0];
  const float* zl = (const float*)d_in[1];
  float* y = (float*)d_out;

  const size_t need = (size_t)kB * kNCH * kCV * sizeof(float4);  // 2 MiB
  if (ws_size >= need) {
    float4* carry = (float4*)d_ws;
    const int n1 = kB * (kNCH - 1) * kCV;   // 122880 -> 480 blocks
    ewrls_carry<<<n1 / 256, 256, 0, stream>>>(x, zl, carry);
    const int n2 = kB * kNCH * kCV;         // 131072 -> 512 blocks
    ewrls_out<<<n2 / 256, 256, 0, stream>>>(x, zl, carry, y);
  } else {
    const int n = kB * kCV;                 // 8192 -> 32 blocks
    ewrls_serial<<<n / 256, 256, 0, stream>>>(x, zl, y);
  }
}

// Round 3
// 260.778 us; speedup vs baseline: 1.0120x; 1.0120x over previous
//
#include <hip/hip_runtime.h>
#include <math.h>

// EWRLS level filter. Reference recurrence collapses:
//   K = P/(lam+P); P' = K  =>  Q=1/P: Q' = lam*Q + 1, Q0 = 1
//   S_t = Q_t * theta_t obeys S_t = lam*S_{t-1} + x_t, S_0 = x_0
//   theta_t = S_t / Q_t,  Q_t = (1 - lam^{t+1}) / (1 - lam)
// Pure per-channel decay scan -> chunked-parallel over T.
//
// R2 -> R3: fix nontemporal builtins (need native ext_vector_type, not
// HIP_vector_type). Otherwise identical to R2: kNCH=32, rcp, unroll 8.

namespace {
constexpr int kB = 64;
constexpr int kT = 1024;
constexpr int kC = 512;
constexpr int kNCH = 32;            // chunks along T
constexpr int kL = kT / kNCH;       // 32 steps per chunk
constexpr int kCV = kC / 4;         // 128 float4 lanes per row
}

typedef float vfloat4 __attribute__((ext_vector_type(4)));

__device__ __forceinline__ void load_lam(const float* __restrict__ zl, int c0,
                                         float lam[4]) {
  vfloat4 z = *reinterpret_cast<const vfloat4*>(zl + c0);
#pragma unroll
  for (int k = 0; k < 4; ++k) {
    float s = 1.0f / (1.0f + expf(-z[k]));
    lam[k] = fminf(fmaxf(s, 1e-4f), 1.0f - 1e-4f);
  }
}

// Phase 1: per-(b, chunk) local decayed sums. Last chunk's carry is never
// consumed, so only kNCH-1 chunks run. Regular (caching) loads: we WANT x
// resident in L3 for phase 2's re-read.
extern "C" __global__ __launch_bounds__(256) void ewrls_carry(
    const float* __restrict__ x, const float* __restrict__ zl,
    vfloat4* __restrict__ carry) {
  int idx = blockIdx.x * 256 + threadIdx.x;
  int cv = idx % kCV;
  int bj = idx / kCV;
  int j = bj % (kNCH - 1);          // wave-uniform: kCV=128 >= 64
  int b = bj / (kNCH - 1);
  float lam[4];
  load_lam(zl, cv * 4, lam);

  const vfloat4* xp = reinterpret_cast<const vfloat4*>(x) +
                      ((size_t)b * kT + (size_t)j * kL) * kCV + cv;
  float s0 = 0.f, s1 = 0.f, s2 = 0.f, s3 = 0.f;
#pragma unroll 8
  for (int t = 0; t < kL; ++t) {
    vfloat4 v = xp[(size_t)t * kCV];
    s0 = fmaf(lam[0], s0, v.x);
    s1 = fmaf(lam[1], s1, v.y);
    s2 = fmaf(lam[2], s2, v.z);
    s3 = fmaf(lam[3], s3, v.w);
  }
  vfloat4 cr = {s0, s1, s2, s3};
  carry[((size_t)b * kNCH + j) * kCV + cv] = cr;
}

// Phase 2: fold predecessor carries (<=31 fmas, wave-uniform trip count),
// seed Q from closed form, scan kL steps, write y = S * rcp(Q).
extern "C" __global__ __launch_bounds__(256) void ewrls_out(
    const float* __restrict__ x, const float* __restrict__ zl,
    const vfloat4* __restrict__ carry, float* __restrict__ y) {
  int idx = blockIdx.x * 256 + threadIdx.x;
  int cv = idx % kCV;
  int bj = idx / kCV;
  int j = bj % kNCH;                // wave-uniform
  int b = bj / kNCH;
  float lam[4];
  load_lam(zl, cv * 4, lam);

  float lamL[4];
#pragma unroll
  for (int k = 0; k < 4; ++k) {
    float p = lam[k];
#pragma unroll
    for (int q = 0; q < 5; ++q) p = p * p;   // lam^32 (kL=32)
    lamL[k] = p;
  }

  float S[4] = {0.f, 0.f, 0.f, 0.f};
  float pj[4] = {1.f, 1.f, 1.f, 1.f};        // lam^(j*kL)
  for (int i = 0; i < j; ++i) {
    vfloat4 cr = carry[((size_t)b * kNCH + i) * kCV + cv];
    S[0] = fmaf(lamL[0], S[0], cr.x);
    S[1] = fmaf(lamL[1], S[1], cr.y);
    S[2] = fmaf(lamL[2], S[2], cr.z);
    S[3] = fmaf(lamL[3], S[3], cr.w);
    pj[0] *= lamL[0];
    pj[1] *= lamL[1];
    pj[2] *= lamL[2];
    pj[3] *= lamL[3];
  }

  float Q[4];
#pragma unroll
  for (int k = 0; k < 4; ++k)
    Q[k] = (1.0f - pj[k]) * __builtin_amdgcn_rcpf(1.0f - lam[k]);

  const size_t base = ((size_t)b * kT + (size_t)j * kL) * kCV + cv;
  const vfloat4* xp = reinterpret_cast<const vfloat4*>(x) + base;
  vfloat4* yp = reinterpret_cast<vfloat4*>(y) + base;
#pragma unroll 8
  for (int t = 0; t < kL; ++t) {
    vfloat4 v = __builtin_nontemporal_load(&xp[(size_t)t * kCV]);
    S[0] = fmaf(lam[0], S[0], v.x);
    S[1] = fmaf(lam[1], S[1], v.y);
    S[2] = fmaf(lam[2], S[2], v.z);
    S[3] = fmaf(lam[3], S[3], v.w);
    Q[0] = fmaf(lam[0], Q[0], 1.0f);
    Q[1] = fmaf(lam[1], Q[1], 1.0f);
    Q[2] = fmaf(lam[2], Q[2], 1.0f);
    Q[3] = fmaf(lam[3], Q[3], 1.0f);
    vfloat4 o;
    o.x = S[0] * __builtin_amdgcn_rcpf(Q[0]);
    o.y = S[1] * __builtin_amdgcn_rcpf(Q[1]);
    o.z = S[2] * __builtin_amdgcn_rcpf(Q[2]);
    o.w = S[3] * __builtin_amdgcn_rcpf(Q[3]);
    __builtin_nontemporal_store(o, &yp[(size_t)t * kCV]);
  }
}

// Fallback if workspace is too small: fully sequential over T per (b, 4ch).
extern "C" __global__ __launch_bounds__(256) void ewrls_serial(
    const float* __restrict__ x, const float* __restrict__ zl,
    float* __restrict__ y) {
  int idx = blockIdx.x * 256 + threadIdx.x;   // [0, kB*kCV)
  int cv = idx % kCV;
  int b = idx / kCV;
  float lam[4];
  load_lam(zl, cv * 4, lam);
  float S[4] = {0.f, 0.f, 0.f, 0.f};
  float Q[4] = {0.f, 0.f, 0.f, 0.f};
  const size_t base = (size_t)b * kT * kCV + cv;
  const vfloat4* xp = reinterpret_cast<const vfloat4*>(x) + base;
  vfloat4* yp = reinterpret_cast<vfloat4*>(y) + base;
#pragma unroll 4
  for (int t = 0; t < kT; ++t) {
    vfloat4 v = xp[(size_t)t * kCV];
    S[0] = fmaf(lam[0], S[0], v.x);
    S[1] = fmaf(lam[1], S[1], v.y);
    S[2] = fmaf(lam[2], S[2], v.z);
    S[3] = fmaf(lam[3], S[3], v.w);
    Q[0] = fmaf(lam[0], Q[0], 1.0f);
    Q[1] = fmaf(lam[1], Q[1], 1.0f);
    Q[2] = fmaf(lam[2], Q[2], 1.0f);
    Q[3] = fmaf(lam[3], Q[3], 1.0f);
    vfloat4 o;
    o.x = S[0] * __builtin_amdgcn_rcpf(Q[0]);
    o.y = S[1] * __builtin_amdgcn_rcpf(Q[1]);
    o.z = S[2] * __builtin_amdgcn_rcpf(Q[2]);
    o.w = S[3] * __builtin_amdgcn_rcpf(Q[3]);
    yp[(size_t)t * kCV] = o;
  }
}

extern "C" void kernel_launch(void* const* d_in, const int* in_sizes, int n_in,
                              void* d_out, int out_size, void* d_ws,
                              size_t ws_size, hipStream_t stream) {
  const float* x = (const float*)d_in[0];
  const float* zl = (const float*)d_in[1];
  float* y = (float*)d_out;

  const size_t need = (size_t)kB * kNCH * kCV * sizeof(vfloat4);  // 4 MiB
  if (ws_size >= need) {
    vfloat4* carry = (vfloat4*)d_ws;
    const int n1 = kB * (kNCH - 1) * kCV;   // 253952 -> 992 blocks
    ewrls_carry<<<n1 / 256, 256, 0, stream>>>(x, zl, carry);
    const int n2 = kB * kNCH * kCV;         // 262144 -> 1024 blocks
    ewrls_out<<<n2 / 256, 256, 0, stream>>>(x, zl, carry, y);
  } else {
    const int n = kB * kCV;                 // 8192 -> 32 blocks
    ewrls_serial<<<n / 256, 256, 0, stream>>>(x, zl, y);
  }
}